// Round 6
// baseline (193.216 us; speedup 1.0000x reference)
//
#include <hip/hip_runtime.h>

#define NF 36
#define QN 100
#define TN 20
#define CN 92
#define NB 64
#define BSTR 136   // row stride (words); [100..135] sentinels (-INF ben / 0 price); 544B rows, 16B-aligned

struct T2 { float v0, v1, p0; int i0; };

// ordered merge: L covers lower q; ties keep L (== lowest-q top_k tie-break). Selection-only: exact.
__device__ __forceinline__ void mergeT(T2& L, const T2& R) {
    if (R.v0 > L.v0) { L.v1 = fmaxf(L.v0, R.v1); L.v0 = R.v0; L.i0 = R.i0; L.p0 = R.p0; }
    else             { L.v1 = fmaxf(R.v0, L.v1); }
}

// one element in ascending-q order; strict > keeps lowest q on ties; tracks price at argmax
__device__ __forceinline__ void elemT(T2& X, float bv, float pv, int q) {
    float v = bv - pv;
    bool c = v > X.v0;
    X.v1 = c ? X.v0 : fmaxf(X.v1, v);
    X.i0 = c ? q : X.i0;
    X.p0 = c ? pv : X.p0;
    X.v0 = c ? v : X.v0;
}

// G lanes per active bidder; each lane scans E=128/G contiguous q's; butterfly-merge; rank-deliver.
template<int G>
__device__ __forceinline__ void scan_deliver(const float (*ben)[BSTR], const float* price,
                                             unsigned long long U, int lane, float eps,
                                             float& mybid, int& bq) {
    constexpr int E = 128 / G;
    constexpr int S = E / 4;
    const int k = lane / G;             // slot index
    const int r = lane % G;
    // slot -> bidder t = k-th set bit of U (dummy-safe for k >= popc)
    unsigned long long u = U;
    #pragma unroll 1
    for (int i = 0; i < k && u; ++i) u &= (u - 1);
    const int t = u ? (int)__builtin_ctzll(u) : 0;
    const float* rb = ben[t];
    const int qb = r * E;

    T2 A{-INFINITY, -INFINITY, 0.f, qb};
    if constexpr (S == 1) {
        float4 bv = *(const float4*)(rb + qb);
        float4 pv = *(const float4*)(price + qb);
        elemT(A, bv.x, pv.x, qb);     elemT(A, bv.y, pv.y, qb + 1);
        elemT(A, bv.z, pv.z, qb + 2); elemT(A, bv.w, pv.w, qb + 3);
    } else {
        constexpr int SH = S / 2;       // chain A = lower half, chain B = upper half (contiguous!)
        T2 B{-INFINITY, -INFINITY, 0.f, qb + SH * 4};
        #pragma unroll
        for (int fi = 0; fi < SH; ++fi) {
            int q = qb + fi * 4;
            float4 bv = *(const float4*)(rb + q);
            float4 pv = *(const float4*)(price + q);
            elemT(A, bv.x, pv.x, q);     elemT(A, bv.y, pv.y, q + 1);
            elemT(A, bv.z, pv.z, q + 2); elemT(A, bv.w, pv.w, q + 3);
        }
        #pragma unroll
        for (int fi = SH; fi < S; ++fi) {
            int q = qb + fi * 4;
            float4 bv = *(const float4*)(rb + q);
            float4 pv = *(const float4*)(price + q);
            elemT(B, bv.x, pv.x, q);     elemT(B, bv.y, pv.y, q + 1);
            elemT(B, bv.z, pv.z, q + 2); elemT(B, bv.w, pv.w, q + 3);
        }
        mergeT(A, B);
    }
    // xor-butterfly, ascending offsets: operands stay contiguous; lower lane = lower q = left
    #pragma unroll
    for (int off = 1; off < G; off <<= 1) {
        T2 R;
        R.v0 = __shfl_xor(A.v0, off);
        R.v1 = __shfl_xor(A.v1, off);
        R.p0 = __shfl_xor(A.p0, off);
        R.i0 = __shfl_xor(A.i0, off);
        bool hi = (lane & off) != 0;
        T2 Lh, Rh;
        Lh.v0 = hi ? R.v0 : A.v0; Lh.v1 = hi ? R.v1 : A.v1; Lh.p0 = hi ? R.p0 : A.p0; Lh.i0 = hi ? R.i0 : A.i0;
        Rh.v0 = hi ? A.v0 : R.v0; Rh.v1 = hi ? A.v1 : R.v1; Rh.p0 = hi ? A.p0 : R.p0; Rh.i0 = hi ? A.i0 : R.i0;
        mergeT(Lh, Rh);
        A = Lh;
    }
    float gbid = A.p0 + (A.v0 - A.v1) + eps;   // exact ref op order
    // deliver slot results to bidder lanes by rank (active lane t: slot < popc -> src in range)
    int slot = (int)__popcll(U & ((1ull << lane) - 1));
    int src = (slot * G) & 63;
    mybid = __shfl(gbid, src);
    bq    = __shfl(A.i0, src);
}

__global__ __launch_bounds__(64) void matcher_kernel(
    const float* __restrict__ logits,   // [64][3600][92]
    const float* __restrict__ pboxes,   // [64][3600][4]
    const int*   __restrict__ tlabels,  // [36][64][20]
    const float* __restrict__ tboxes,   // [36][64][20][4]
    float* __restrict__ out_cost,       // [64][36][100][20]
    float* __restrict__ out_pred,       // [64][36][20]
    float* __restrict__ out_tgt)        // [64][36][20]
{
    const int bf = blockIdx.x;          // b*36 + f
    const int b  = bf / NF;
    const int f  = bf % NF;
    const int lane = threadIdx.x;

    __shared__ __align__(16) float ben[TN][BSTR];  // benefit[t][q] = -cost[q][t]
    __shared__ __align__(16) float price[BSTR];
    __shared__ int   objl[TN];
    __shared__ int   slab[TN];
    __shared__ float tbr[TN][4];        // raw cxcywh
    __shared__ float tbx[TN][4];        // xyxy
    __shared__ float tarea[TN];

    // ---- stage targets ----
    if (lane < TN) {
        const int base = (f * NB + b) * TN + lane;
        slab[lane] = tlabels[base];
        const float* tb = tboxes + (size_t)base * 4;
        float cx = tb[0], cy = tb[1], w = tb[2], h = tb[3];
        tbr[lane][0] = cx; tbr[lane][1] = cy; tbr[lane][2] = w; tbr[lane][3] = h;
        float x1 = cx - 0.5f * w, y1 = cy - 0.5f * h;
        float x2 = cx + 0.5f * w, y2 = cy + 0.5f * h;
        tbx[lane][0] = x1; tbx[lane][1] = y1; tbx[lane][2] = x2; tbx[lane][3] = y2;
        tarea[lane] = (x2 - x1) * (y2 - y1);
    }
    __syncthreads();

    // ---- cost phase: register-resident logits, 2 passes over q ----
    float mn = INFINITY, mx = -INFINITY;
    for (int p = 0; p < 2; ++p) {
        const int q = lane + 64 * p;
        if (q < QN) {
            const size_t row = (size_t)b * (NF * QN) + (size_t)f * QN + q;
            const float* L = logits + row * CN;
            const float4* L4 = reinterpret_cast<const float4*>(L);
            float4 r[23];
            #pragma unroll
            for (int i = 0; i < 23; ++i) r[i] = L4[i];
            // sequential c-order max then exp-sum (bit-identical to passing kernels)
            float m = -INFINITY;
            #pragma unroll
            for (int i = 0; i < 23; ++i) {
                float4 v = r[i];
                m = fmaxf(m, v.x); m = fmaxf(m, v.y); m = fmaxf(m, v.z); m = fmaxf(m, v.w);
            }
            float s = 0.f;
            #pragma unroll
            for (int i = 0; i < 23; ++i) {
                float4 v = r[i];
                s += expf(v.x - m); s += expf(v.y - m); s += expf(v.z - m); s += expf(v.w - m);
            }

            float4 pbv = reinterpret_cast<const float4*>(pboxes)[row];
            float cx = pbv.x, cy = pbv.y, w = pbv.z, h = pbv.w;
            float px1 = cx - 0.5f * w, py1 = cy - 0.5f * h;
            float px2 = cx + 0.5f * w, py2 = cy + 0.5f * h;
            float a1 = (px2 - px1) * (py2 - py1);

            for (int t = 0; t < TN; ++t) {
                float pc = expf(L[slab[t]] - m) / s;   // L1/L2-warm gather
                float cb = fabsf(cx - tbr[t][0]) + fabsf(cy - tbr[t][1]);
                cb = cb + fabsf(w - tbr[t][2]);
                cb = cb + fabsf(h - tbr[t][3]);
                float ltx = fmaxf(px1, tbx[t][0]), lty = fmaxf(py1, tbx[t][1]);
                float rbx = fminf(px2, tbx[t][2]), rby = fminf(py2, tbx[t][3]);
                float wx = fmaxf(rbx - ltx, 0.f), wy = fmaxf(rby - lty, 0.f);
                float inter = wx * wy;
                float uni = a1 + tarea[t] - inter;
                float iou = inter / uni;
                float ex1 = fminf(px1, tbx[t][0]), ey1 = fminf(py1, tbx[t][1]);
                float ex2 = fmaxf(px2, tbx[t][2]), ey2 = fmaxf(py2, tbx[t][3]);
                float ew = fmaxf(ex2 - ex1, 0.f), eh = fmaxf(ey2 - ey1, 0.f);
                float ae = ew * eh;
                float giou = iou - (ae - uni) / ae;
                float cost = (-pc) + 5.0f * cb - 2.0f * giou;
                ben[t][q] = -cost;
                mn = fminf(mn, cost);
                mx = fmaxf(mx, cost);
            }
        }
    }

    // init price + sentinels: price[0..135]=0, ben[t][100..135]=-INF
    for (int i = lane; i < BSTR; i += 64) price[i] = 0.f;
    for (int i = lane; i < TN * (BSTR - QN); i += 64) {
        int t = i / (BSTR - QN);
        int qq = QN + (i - t * (BSTR - QN));
        ben[t][qq] = -INFINITY;
    }
    __syncthreads();

    // eps (exact: spread = (-mn)-(-mx)+1e-6, /1000) — min/max order-free
    #pragma unroll
    for (int off = 32; off > 0; off >>= 1) {
        mn = fminf(mn, __shfl_xor(mn, off, 64));
        mx = fmaxf(mx, __shfl_xor(mx, off, 64));
    }
    const float eps = (((-mn) - (-mx)) + 1e-6f) / 1000.0f;

    // coalesced cost write-out from LDS
    {
        float4* dst = reinterpret_cast<float4*>(out_cost + (size_t)bf * (QN * TN));
        for (int i = lane; i < (QN * TN) / 4; i += 64) {
            int k = i * 4;
            int q = k / TN, t0 = k - q * TN;   // 20%4==0: never spans q
            float4 v;
            v.x = -ben[t0 + 0][q]; v.y = -ben[t0 + 1][q];
            v.z = -ben[t0 + 2][q]; v.w = -ben[t0 + 3][q];
            dst[i] = v;
        }
    }
    __syncthreads();

    // ---- auction: Jacobi, exact reference dynamics; bidder/owner state on lane t<20 ----
    const float (*benc)[BSTR] = (const float (*)[BSTR])ben;
    int myobj = -1;
    for (int it = 0; it < 20000; ++it) {
        const bool active = (lane < TN) && (myobj < 0);
        unsigned long long U = __ballot(active);
        if (U == 0ull) break;
        const int popc = (int)__popcll(U);

        float mybid; int bq;
        if      (popc <= 2)  scan_deliver<32>(benc, price, U, lane, eps, mybid, bq);
        else if (popc <= 4)  scan_deliver<16>(benc, price, U, lane, eps, mybid, bq);
        else if (popc <= 8)  scan_deliver<8 >(benc, price, U, lane, eps, mybid, bq);
        else if (popc <= 16) scan_deliver<4 >(benc, price, U, lane, eps, mybid, bq);
        else                 scan_deliver<2 >(benc, price, U, lane, eps, mybid, bq);

        // resolution: winner of q = max-bid (lowest t on ties) among active bidders on q;
        // an owner is evicted iff anyone bids on its object.
        bool lose = false, evicted = false;
        if (popc == 1) {
            int src = (int)__builtin_ctzll(U);   // sole bidder always wins
            int sq = __shfl(bq, src);
            evicted = (myobj == sq);
        } else {
            float sendb = active ? mybid : -INFINITY;
            unsigned long long u = U;
            while (u) {
                int t2 = (int)__builtin_ctzll(u); u &= (u - 1);
                float sb = __shfl(sendb, t2);
                int   sq = __shfl(bq, t2);
                lose    = lose    || (sq == bq   && (sb > mybid || (sb == mybid && t2 < lane)));
                evicted = evicted || (sq == myobj);
            }
        }
        if (active && !lose) { price[bq] = mybid; myobj = bq; }   // winners: distinct q
        else if (evicted && myobj >= 0) myobj = -1;               // evictees disjoint from winners
        __syncthreads();   // publish price updates for next iteration's scan
    }
    if (lane < TN) objl[lane] = myobj;
    __syncthreads();

    // ---- stable argsort of obj_of (rank computation) ----
    if (lane < TN) {
        int v = objl[lane];
        int r = 0;
        for (int u = 0; u < TN; ++u) {
            int w = objl[u];
            r += (w < v) || (w == v && u < lane);
        }
        out_pred[(size_t)bf * TN + r] = (float)v;
        out_tgt[(size_t)bf * TN + r]  = (float)lane;
    }
}

extern "C" void kernel_launch(void* const* d_in, const int* in_sizes, int n_in,
                              void* d_out, int out_size, void* d_ws, size_t ws_size,
                              hipStream_t stream) {
    const float* logits  = (const float*)d_in[0];
    const float* pboxes  = (const float*)d_in[1];
    const int*   tlabels = (const int*)d_in[2];
    const float* tboxes  = (const float*)d_in[3];

    float* out = (float*)d_out;
    float* out_cost = out;                                   // 64*36*100*20
    float* out_pred = out + (size_t)NB * NF * QN * TN;       // 64*36*20
    float* out_tgt  = out_pred + (size_t)NB * NF * TN;       // 64*36*20

    hipLaunchKernelGGL(matcher_kernel, dim3(NB * NF), dim3(64), 0, stream,
                       logits, pboxes, tlabels, tboxes, out_cost, out_pred, out_tgt);
}